// Round 14
// baseline (155.881 us; speedup 1.0000x reference)
//
#include <hip/hip_runtime.h>

#define NN 100000
#define NE 1600000
#define FIN 32
#define FHID 64

#define CLB 8                                   // log2(nodes per bucket)
#define BN (1 << CLB)                           // 256 nodes / bucket
#define NB ((NN + BN - 1) / BN)                 // 391 buckets
#define CAP 6000                                // record capacity per bucket (+30 sigma)
#define NDB 512                                 // distributor blocks
#define NDT 256                                 // distributor threads
#define CHUNK ((NE + NDB - 1) / NDB)            // 3125 edges / distributor block
#define RCAP 12                                 // 512*12 = 6144 >= CAP

#define LGKM0 asm volatile("s_waitcnt lgkmcnt(0)" ::: "memory")

__device__ __forceinline__ float lo16(unsigned g) {
    return __uint_as_float(g << 16);
}
__device__ __forceinline__ float hi16(unsigned g) {
    return __uint_as_float(g & 0xFFFF0000u);
}
__device__ __forceinline__ unsigned pack_bf16(float a, float b) {
    unsigned ua = __float_as_uint(a);
    unsigned ub = __float_as_uint(b);
    ua += 0x7FFFu + ((ua >> 16) & 1u);          // RNE
    ub += 0x7FFFu + ((ub >> 16) & 1u);
    return (ua >> 16) | (ub & 0xFFFF0000u);
}

// ---------- distribute: LDS hist -> atomic slice reservation -> write ---------
// record = ((col_local << 17) | src, ew_bits); fused edge_attr passthrough.
__global__ __launch_bounds__(NDT) void k_dwrite(
        const int* __restrict__ row, const int* __restrict__ col,
        const float* __restrict__ ea, int* __restrict__ cnt_g,
        uint2* __restrict__ rec0, float* __restrict__ out_ea) {
    __shared__ int hc[NB];
    __shared__ int bl[NB];
    int tid = threadIdx.x;
    for (int i = tid; i < NB; i += NDT) hc[i] = 0;
    __syncthreads();
    int beg = blockIdx.x * CHUNK, end = min(beg + CHUNK, NE);
    for (int e = beg + tid; e < end; e += NDT)
        atomicAdd(&hc[col[e] >> CLB], 1);
    __syncthreads();
    for (int i = tid; i < NB; i += NDT) {
        int c = hc[i];
        bl[i] = i * CAP + (c ? atomicAdd(&cnt_g[i], c) : 0);
        hc[i] = 0;                              // reuse as local rank
    }
    __syncthreads();
    for (int e = beg + tid; e < end; e += NDT) {
        int c = col[e];
        int bk = c >> CLB;
        int r = atomicAdd(&hc[bk], 1);
        float w = ea[e];
        rec0[bl[bk] + r] = make_uint2(((unsigned)(c & (BN - 1)) << 17) |
                                          (unsigned)row[e],
                                      __float_as_uint(w));
        out_ea[e] = w;                          // fused passthrough output
    }
}

// ---------- per-bucket sort -> packed rowptr + dinv + xp packing --------------
// rowptrp[n] = (csr_pos << 10) | in_degree   (pos < 2^22, deg < 1024)
__global__ __launch_bounds__(512) void k_bsort(
        const int* __restrict__ cnt_g, const uint2* __restrict__ rec0,
        const float* __restrict__ x, uint2* __restrict__ csr,
        unsigned* __restrict__ rowptrp, float* __restrict__ dinv,
        unsigned* __restrict__ xp) {
    __shared__ int cnt[BN];
    __shared__ int bas[BN];
    __shared__ int cur[BN];
    __shared__ float dg[BN];
    __shared__ float dl[BN];
    int tid = threadIdx.x;
    int b = blockIdx.x;
    int base = b * CAP;
    int m = cnt_g[b];
    if (tid < BN) { cnt[tid] = 0; dg[tid] = 0.0f; }
    __syncthreads();
    uint2 rc[RCAP];
#pragma unroll
    for (int i = 0; i < RCAP; ++i) {
        int j = tid + i * 512;
        if (j < m) {
            uint2 p = rec0[base + j];
            rc[i] = p;
            atomicAdd(&cnt[p.x >> 17], 1);
            atomicAdd(&dg[p.x >> 17], __uint_as_float(p.y));
        } else {
            rc[i] = make_uint2(0u, 0u);
        }
    }
    __syncthreads();
    int v0 = (tid < BN) ? cnt[tid] : 0;
    __syncthreads();
    for (int o = 1; o < BN; o <<= 1) {               // Hillis-Steele inclusive
        int t = (tid < BN && tid >= o) ? cnt[tid - o] : 0;
        __syncthreads();
        if (tid < BN) cnt[tid] += t;
        __syncthreads();
    }
    if (tid < BN) {
        int excl = cnt[tid] - v0;
        bas[tid] = excl;
        cur[tid] = 0;
        float dn = rsqrtf(1.0f + dg[tid]);           // self-loop weight 1
        dl[tid] = dn;
        int node = b * BN + tid;
        if (node < NN) {
            rowptrp[node] = ((unsigned)(base + excl) << 10) | (unsigned)v0;
            dinv[node] = dn;
        }
    }
    __syncthreads();
#pragma unroll
    for (int i = 0; i < RCAP; ++i) {
        int j = tid + i * 512;
        if (j < m) {
            uint2 p = rc[i];
            int cl = p.x >> 17;
            int r = atomicAdd(&cur[cl], 1);
            csr[base + bas[cl] + r] = make_uint2(p.x & 0x1FFFFu, p.y);
        }
    }
    // fused scalex: xp = bf16x2(dinv * x) for this bucket's nodes
    for (int idx = tid; idx < BN * (FIN / 2); idx += 512) {
        int nl = idx >> 4;
        int node = b * BN + nl;
        if (node >= NN) break;
        float dn = dl[nl];
        float2 v = ((const float2*)x)[(size_t)node * 16 + (idx & 15)];
        xp[(size_t)node * 16 + (idx & 15)] = pack_bf16(v.x * dn, v.y * dn);
    }
}

// ---------- pure aggregation, 2 nodes/wave, 4-deep gather unroll --------------
__global__ __launch_bounds__(256) void k_agg1p(
        const unsigned* __restrict__ rowptrp, const uint2* __restrict__ csr,
        const uint2* __restrict__ xp2, const float* __restrict__ dinv,
        uint2* __restrict__ pre) {
    int wid = (blockIdx.x * blockDim.x + threadIdx.x) >> 6;
    int lane = threadIdx.x & 63;
    int n = wid * 2 + (lane >> 5);
    if (n >= NN) return;
    int s = (lane & 31) >> 3;
    int u = lane & 7;
    unsigned rp = rowptrp[n];
    int beg = rp >> 10;
    int end = beg + (rp & 1023u);
    float dn = dinv[n];
    uint2 gs = xp2[(size_t)n * 8 + u];
    float c0 = 0.f, c1 = 0.f, c2 = 0.f, c3 = 0.f;
    float d0 = 0.f, d1 = 0.f, d2 = 0.f, d3 = 0.f;
    int j = beg + s;
    for (; j + 12 < end; j += 16) {
        uint2 e0 = csr[j];
        uint2 e1 = csr[j + 4];
        uint2 e2 = csr[j + 8];
        uint2 e3 = csr[j + 12];
        uint2 g0 = xp2[(size_t)e0.x * 8 + u];
        uint2 g1 = xp2[(size_t)e1.x * 8 + u];
        uint2 g2 = xp2[(size_t)e2.x * 8 + u];
        uint2 g3 = xp2[(size_t)e3.x * 8 + u];
        float w0 = __uint_as_float(e0.y);
        float w1 = __uint_as_float(e1.y);
        float w2 = __uint_as_float(e2.y);
        float w3 = __uint_as_float(e3.y);
        c0 = fmaf(w0, lo16(g0.x), c0);
        c1 = fmaf(w0, hi16(g0.x), c1);
        c2 = fmaf(w0, lo16(g0.y), c2);
        c3 = fmaf(w0, hi16(g0.y), c3);
        d0 = fmaf(w1, lo16(g1.x), d0);
        d1 = fmaf(w1, hi16(g1.x), d1);
        d2 = fmaf(w1, lo16(g1.y), d2);
        d3 = fmaf(w1, hi16(g1.y), d3);
        c0 = fmaf(w2, lo16(g2.x), c0);
        c1 = fmaf(w2, hi16(g2.x), c1);
        c2 = fmaf(w2, lo16(g2.y), c2);
        c3 = fmaf(w2, hi16(g2.y), c3);
        d0 = fmaf(w3, lo16(g3.x), d0);
        d1 = fmaf(w3, hi16(g3.x), d1);
        d2 = fmaf(w3, lo16(g3.y), d2);
        d3 = fmaf(w3, hi16(g3.y), d3);
    }
    for (; j < end; j += 4) {
        uint2 e = csr[j];
        uint2 g = xp2[(size_t)e.x * 8 + u];
        float w = __uint_as_float(e.y);
        c0 = fmaf(w, lo16(g.x), c0);
        c1 = fmaf(w, hi16(g.x), c1);
        c2 = fmaf(w, lo16(g.y), c2);
        c3 = fmaf(w, hi16(g.y), c3);
    }
    c0 += d0; c1 += d1; c2 += d2; c3 += d3;
#pragma unroll
    for (int m = 8; m <= 16; m <<= 1) {          // reduce across 4 slots
        c0 += __shfl_xor(c0, m, 64);
        c1 += __shfl_xor(c1, m, 64);
        c2 += __shfl_xor(c2, m, 64);
        c3 += __shfl_xor(c3, m, 64);
    }
    if (s == 0) {
        float p0 = dn * (c0 + lo16(gs.x));
        float p1 = dn * (c1 + hi16(gs.x));
        float p2 = dn * (c2 + lo16(gs.y));
        float p3 = dn * (c3 + hi16(gs.y));
        pre[(size_t)n * 8 + u] = make_uint2(pack_bf16(p0, p1), pack_bf16(p2, p3));
    }
}

// ---------- dense MLP: pre -> GEMM1(+b1,relu) -> GEMM2 -> dn scale -> hw2p ----
__global__ __launch_bounds__(256) void k_mlp(
        const uint2* __restrict__ pre2, const float* __restrict__ dinv,
        const float* __restrict__ W1, const float* __restrict__ b1,
        const float* __restrict__ W2, unsigned* __restrict__ hw2p, int nwaves) {
    __shared__ float pre_lds[4 * FIN];
    __shared__ float hv_lds[4 * FHID];
    int lane = threadIdx.x & 63;
    int ws = threadIdx.x >> 6;
    int hh = lane >> 5;
    int f = lane & 31;
    int t = lane & 15;
    int o = lane;
    float W1col[FIN];
#pragma unroll
    for (int k = 0; k < FIN; ++k) W1col[k] = W1[k * FHID + o];
    float b1o = b1[o];
    float W2h[FIN];
#pragma unroll
    for (int k = 0; k < FIN; ++k) W2h[k] = W2[(hh * 32 + k) * FIN + f];

    int gw = (blockIdx.x * blockDim.x + threadIdx.x) >> 6;
    for (int n = gw; n < NN; n += nwaves) {
        float dn = dinv[n];
        if (lane < 8) {
            uint2 g = pre2[(size_t)n * 8 + lane];
            float4 pq = make_float4(lo16(g.x), hi16(g.x), lo16(g.y), hi16(g.y));
            *(float4*)&pre_lds[ws * FIN + 4 * lane] = pq;
        }
        LGKM0;
        float hacc = b1o;
#pragma unroll
        for (int i = 0; i < 8; ++i) {
            float4 qd = *(const float4*)&pre_lds[ws * FIN + 4 * i];
            hacc = fmaf(qd.x, W1col[4 * i + 0], hacc);
            hacc = fmaf(qd.y, W1col[4 * i + 1], hacc);
            hacc = fmaf(qd.z, W1col[4 * i + 2], hacc);
            hacc = fmaf(qd.w, W1col[4 * i + 3], hacc);
        }
        hacc = hacc > 0.0f ? hacc : 0.0f;
        hv_lds[ws * FHID + o] = hacc;
        LGKM0;
        float part = 0.0f;
#pragma unroll
        for (int i = 0; i < 8; ++i) {
            float4 qd = *(const float4*)&hv_lds[ws * FHID + hh * 32 + 4 * i];
            part = fmaf(qd.x, W2h[4 * i + 0], part);
            part = fmaf(qd.y, W2h[4 * i + 1], part);
            part = fmaf(qd.z, W2h[4 * i + 2], part);
            part = fmaf(qd.w, W2h[4 * i + 3], part);
        }
        part += __shfl_xor(part, 32, 64);
        float v = dn * part;
        float vlo = __shfl(v, 2 * t, 64);
        float vhi = __shfl(v, 2 * t + 1, 64);
        if (lane < 16) hw2p[(size_t)n * 16 + lane] = pack_bf16(vlo, vhi);
    }
}

// ---------- layer-2 pure aggregation, 2 nodes/wave, +bias+relu -> out ---------
__global__ __launch_bounds__(256) void k_agg2p(
        const unsigned* __restrict__ rowptrp, const uint2* __restrict__ csr,
        const uint2* __restrict__ hw2p2, const float* __restrict__ dinv,
        const float* __restrict__ b2, float* __restrict__ out) {
    int wid = (blockIdx.x * blockDim.x + threadIdx.x) >> 6;
    int lane = threadIdx.x & 63;
    int n = wid * 2 + (lane >> 5);
    if (n >= NN) return;
    int s = (lane & 31) >> 3;
    int u = lane & 7;
    unsigned rp = rowptrp[n];
    int beg = rp >> 10;
    int end = beg + (rp & 1023u);
    float dn = dinv[n];
    uint2 gs = hw2p2[(size_t)n * 8 + u];
    float c0 = 0.f, c1 = 0.f, c2 = 0.f, c3 = 0.f;
    float d0 = 0.f, d1 = 0.f, d2 = 0.f, d3 = 0.f;
    int j = beg + s;
    for (; j + 12 < end; j += 16) {
        uint2 e0 = csr[j];
        uint2 e1 = csr[j + 4];
        uint2 e2 = csr[j + 8];
        uint2 e3 = csr[j + 12];
        uint2 g0 = hw2p2[(size_t)e0.x * 8 + u];
        uint2 g1 = hw2p2[(size_t)e1.x * 8 + u];
        uint2 g2 = hw2p2[(size_t)e2.x * 8 + u];
        uint2 g3 = hw2p2[(size_t)e3.x * 8 + u];
        float w0 = __uint_as_float(e0.y);
        float w1 = __uint_as_float(e1.y);
        float w2 = __uint_as_float(e2.y);
        float w3 = __uint_as_float(e3.y);
        c0 = fmaf(w0, lo16(g0.x), c0);
        c1 = fmaf(w0, hi16(g0.x), c1);
        c2 = fmaf(w0, lo16(g0.y), c2);
        c3 = fmaf(w0, hi16(g0.y), c3);
        d0 = fmaf(w1, lo16(g1.x), d0);
        d1 = fmaf(w1, hi16(g1.x), d1);
        d2 = fmaf(w1, lo16(g1.y), d2);
        d3 = fmaf(w1, hi16(g1.y), d3);
        c0 = fmaf(w2, lo16(g2.x), c0);
        c1 = fmaf(w2, hi16(g2.x), c1);
        c2 = fmaf(w2, lo16(g2.y), c2);
        c3 = fmaf(w2, hi16(g2.y), c3);
        d0 = fmaf(w3, lo16(g3.x), d0);
        d1 = fmaf(w3, hi16(g3.x), d1);
        d2 = fmaf(w3, lo16(g3.y), d2);
        d3 = fmaf(w3, hi16(g3.y), d3);
    }
    for (; j < end; j += 4) {
        uint2 e = csr[j];
        uint2 g = hw2p2[(size_t)e.x * 8 + u];
        float w = __uint_as_float(e.y);
        c0 = fmaf(w, lo16(g.x), c0);
        c1 = fmaf(w, hi16(g.x), c1);
        c2 = fmaf(w, lo16(g.y), c2);
        c3 = fmaf(w, hi16(g.y), c3);
    }
    c0 += d0; c1 += d1; c2 += d2; c3 += d3;
#pragma unroll
    for (int m = 8; m <= 16; m <<= 1) {
        c0 += __shfl_xor(c0, m, 64);
        c1 += __shfl_xor(c1, m, 64);
        c2 += __shfl_xor(c2, m, 64);
        c3 += __shfl_xor(c3, m, 64);
    }
    if (s == 0) {
        float4 bq = ((const float4*)b2)[u];
        float4 v;
        v.x = dn * (c0 + lo16(gs.x)) + bq.x;
        v.y = dn * (c1 + hi16(gs.x)) + bq.y;
        v.z = dn * (c2 + lo16(gs.y)) + bq.z;
        v.w = dn * (c3 + hi16(gs.y)) + bq.w;
        v.x = v.x > 0.f ? v.x : 0.f;
        v.y = v.y > 0.f ? v.y : 0.f;
        v.z = v.z > 0.f ? v.z : 0.f;
        v.w = v.w > 0.f ? v.w : 0.f;
        ((float4*)out)[(size_t)n * 8 + u] = v;
    }
}

extern "C" void kernel_launch(void* const* d_in, const int* in_sizes, int n_in,
                              void* d_out, int out_size, void* d_ws, size_t ws_size,
                              hipStream_t stream) {
    const float* x  = (const float*)d_in[0];
    const int*   ei = (const int*)d_in[1];
    const float* ea = (const float*)d_in[2];
    const float* W1 = (const float*)d_in[3];
    const float* b1 = (const float*)d_in[4];
    const float* W2 = (const float*)d_in[5];
    const float* b2 = (const float*)d_in[6];
    float* out = (float*)d_out;

    const int* row = ei;        // edge_index[0]
    const int* col = ei + NE;   // edge_index[1]

    // workspace layout (~58 MB)
    char* w = (char*)d_ws;
    uint2* rec0     = (uint2*)w;                         // NB*CAP*8  (18.8 MB)
    uint2* csr      = rec0 + (size_t)NB * CAP;           // NB*CAP*8  (18.8 MB)
    unsigned* xp    = (unsigned*)(csr + (size_t)NB * CAP);   // NN*16 (bf16x2)
    unsigned* hw2p  = xp + (size_t)NN * 16;              // NN*16 (bf16x2)
    unsigned* pre   = hw2p + (size_t)NN * 16;            // NN*16 (bf16x2)
    float* dinv     = (float*)(pre + (size_t)NN * 16);   // NN
    unsigned* rowptrp = (unsigned*)(dinv + NN);          // NN
    int*   cnt_g    = (int*)(rowptrp + NN);              // NB

    auto cdiv = [](long long a, int b) { return (int)((a + b - 1) / b); };
    const int PAIR_BLOCKS = cdiv((long long)cdiv(NN, 2) * 64, 256);  // 12500

    // build: zero bucket cursors, distribute (+ea passthrough), bucket sort
    hipMemsetAsync(cnt_g, 0, sizeof(int) * NB, stream);
    k_dwrite<<<NDB, NDT, 0, stream>>>(row, col, ea, cnt_g, rec0,
                                      out + (size_t)NN * FIN);
    k_bsort<<<NB, 512, 0, stream>>>(cnt_g, rec0, x, csr, rowptrp, dinv, xp);

    // layer 1: pure agg -> pre (bf16), dense MLP -> hw2p (bf16)
    k_agg1p<<<PAIR_BLOCKS, 256, 0, stream>>>(rowptrp, csr, (const uint2*)xp,
                                             dinv, (uint2*)pre);
    const int MLP_BLOCKS = 2048;
    k_mlp<<<MLP_BLOCKS, 256, 0, stream>>>((const uint2*)pre, dinv, W1, b1, W2,
                                          hw2p, MLP_BLOCKS * 4);

    // layer 2: pure agg (+bias, relu) -> out
    k_agg2p<<<PAIR_BLOCKS, 256, 0, stream>>>(rowptrp, csr, (const uint2*)hw2p,
                                             dinv, b2, out);
}

// Round 15
// 148.941 us; speedup vs baseline: 1.0466x; 1.0466x over previous
//
#include <hip/hip_runtime.h>

#define NN 100000
#define NE 1600000
#define FIN 32
#define FHID 64

#define CLB 8                                   // log2(nodes per bucket)
#define BN (1 << CLB)                           // 256 nodes / bucket
#define NB ((NN + BN - 1) / BN)                 // 391 buckets
#define CAP 6000                                // record capacity per bucket (+30 sigma)
#define NDB 512                                 // distributor blocks
#define NDT 1024                                // distributor threads (16 waves)
#define CHUNK ((NE + NDB - 1) / NDB)            // 3125 edges / distributor block
#define RCAP 12                                 // 512*12 = 6144 >= CAP

#define LGKM0 asm volatile("s_waitcnt lgkmcnt(0)" ::: "memory")

__device__ __forceinline__ float lo16(unsigned g) {
    return __uint_as_float(g << 16);
}
__device__ __forceinline__ float hi16(unsigned g) {
    return __uint_as_float(g & 0xFFFF0000u);
}
__device__ __forceinline__ unsigned pack_bf16(float a, float b) {
    unsigned ua = __float_as_uint(a);
    unsigned ub = __float_as_uint(b);
    ua += 0x7FFFu + ((ua >> 16) & 1u);          // RNE
    ub += 0x7FFFu + ((ub >> 16) & 1u);
    return (ua >> 16) | (ub & 0xFFFF0000u);
}

// ---------- distribute: LDS hist -> atomic slice reservation -> write ---------
// record = ((col_local << 17) | src, ew_bits); fused edge_attr passthrough.
__global__ __launch_bounds__(NDT) void k_dwrite(
        const int* __restrict__ row, const int* __restrict__ col,
        const float* __restrict__ ea, int* __restrict__ cnt_g,
        uint2* __restrict__ rec0, float* __restrict__ out_ea) {
    __shared__ int hc[NB];
    __shared__ int bl[NB];
    int tid = threadIdx.x;
    for (int i = tid; i < NB; i += NDT) hc[i] = 0;
    __syncthreads();
    int beg = blockIdx.x * CHUNK, end = min(beg + CHUNK, NE);
    for (int e = beg + tid; e < end; e += NDT)
        atomicAdd(&hc[col[e] >> CLB], 1);
    __syncthreads();
    for (int i = tid; i < NB; i += NDT) {
        int c = hc[i];
        bl[i] = i * CAP + (c ? atomicAdd(&cnt_g[i], c) : 0);
        hc[i] = 0;                              // reuse as local rank
    }
    __syncthreads();
    for (int e = beg + tid; e < end; e += NDT) {
        int c = col[e];
        int bk = c >> CLB;
        int r = atomicAdd(&hc[bk], 1);
        float w = ea[e];
        rec0[bl[bk] + r] = make_uint2(((unsigned)(c & (BN - 1)) << 17) |
                                          (unsigned)row[e],
                                      __float_as_uint(w));
        out_ea[e] = w;                          // fused passthrough output
    }
}

// ---------- per-bucket sort -> packed rowptr + dinv + xp packing --------------
// rowptrp[n] = (csr_pos << 10) | in_degree   (pos < 2^22, deg < 1024)
__global__ __launch_bounds__(512) void k_bsort(
        const int* __restrict__ cnt_g, const uint2* __restrict__ rec0,
        const float* __restrict__ x, uint2* __restrict__ csr,
        unsigned* __restrict__ rowptrp, float* __restrict__ dinv,
        unsigned* __restrict__ xp) {
    __shared__ int cnt[BN];
    __shared__ int bas[BN];
    __shared__ int cur[BN];
    __shared__ float dg[BN];
    __shared__ float dl[BN];
    int tid = threadIdx.x;
    int b = blockIdx.x;
    int base = b * CAP;
    int m = cnt_g[b];
    if (tid < BN) { cnt[tid] = 0; dg[tid] = 0.0f; }
    __syncthreads();
    uint2 rc[RCAP];
#pragma unroll
    for (int i = 0; i < RCAP; ++i) {
        int j = tid + i * 512;
        if (j < m) {
            uint2 p = rec0[base + j];
            rc[i] = p;
            atomicAdd(&cnt[p.x >> 17], 1);
            atomicAdd(&dg[p.x >> 17], __uint_as_float(p.y));
        } else {
            rc[i] = make_uint2(0u, 0u);
        }
    }
    __syncthreads();
    int v0 = (tid < BN) ? cnt[tid] : 0;
    __syncthreads();
    for (int o = 1; o < BN; o <<= 1) {               // Hillis-Steele inclusive
        int t = (tid < BN && tid >= o) ? cnt[tid - o] : 0;
        __syncthreads();
        if (tid < BN) cnt[tid] += t;
        __syncthreads();
    }
    if (tid < BN) {
        int excl = cnt[tid] - v0;
        bas[tid] = excl;
        cur[tid] = 0;
        float dn = rsqrtf(1.0f + dg[tid]);           // self-loop weight 1
        dl[tid] = dn;
        int node = b * BN + tid;
        if (node < NN) {
            rowptrp[node] = ((unsigned)(base + excl) << 10) | (unsigned)v0;
            dinv[node] = dn;
        }
    }
    __syncthreads();
#pragma unroll
    for (int i = 0; i < RCAP; ++i) {
        int j = tid + i * 512;
        if (j < m) {
            uint2 p = rc[i];
            int cl = p.x >> 17;
            int r = atomicAdd(&cur[cl], 1);
            csr[base + bas[cl] + r] = make_uint2(p.x & 0x1FFFFu, p.y);
        }
    }
    // fused scalex: xp = bf16x2(dinv * x) for this bucket's nodes
    for (int idx = tid; idx < BN * (FIN / 2); idx += 512) {
        int nl = idx >> 4;
        int node = b * BN + nl;
        if (node >= NN) break;
        float dn = dl[nl];
        float2 v = ((const float2*)x)[(size_t)node * 16 + (idx & 15)];
        xp[(size_t)node * 16 + (idx & 15)] = pack_bf16(v.x * dn, v.y * dn);
    }
}

// ---------- pure aggregation, 2 nodes/wave, 4-deep gather unroll --------------
__global__ __launch_bounds__(256) void k_agg1p(
        const unsigned* __restrict__ rowptrp, const uint2* __restrict__ csr,
        const uint2* __restrict__ xp2, const float* __restrict__ dinv,
        uint2* __restrict__ pre) {
    int wid = (blockIdx.x * blockDim.x + threadIdx.x) >> 6;
    int lane = threadIdx.x & 63;
    int n = wid * 2 + (lane >> 5);
    if (n >= NN) return;
    int s = (lane & 31) >> 3;
    int u = lane & 7;
    unsigned rp = rowptrp[n];
    int beg = rp >> 10;
    int end = beg + (rp & 1023u);
    float dn = dinv[n];
    uint2 gs = xp2[(size_t)n * 8 + u];
    float c0 = 0.f, c1 = 0.f, c2 = 0.f, c3 = 0.f;
    float d0 = 0.f, d1 = 0.f, d2 = 0.f, d3 = 0.f;
    int j = beg + s;
    for (; j + 12 < end; j += 16) {
        uint2 e0 = csr[j];
        uint2 e1 = csr[j + 4];
        uint2 e2 = csr[j + 8];
        uint2 e3 = csr[j + 12];
        uint2 g0 = xp2[(size_t)e0.x * 8 + u];
        uint2 g1 = xp2[(size_t)e1.x * 8 + u];
        uint2 g2 = xp2[(size_t)e2.x * 8 + u];
        uint2 g3 = xp2[(size_t)e3.x * 8 + u];
        float w0 = __uint_as_float(e0.y);
        float w1 = __uint_as_float(e1.y);
        float w2 = __uint_as_float(e2.y);
        float w3 = __uint_as_float(e3.y);
        c0 = fmaf(w0, lo16(g0.x), c0);
        c1 = fmaf(w0, hi16(g0.x), c1);
        c2 = fmaf(w0, lo16(g0.y), c2);
        c3 = fmaf(w0, hi16(g0.y), c3);
        d0 = fmaf(w1, lo16(g1.x), d0);
        d1 = fmaf(w1, hi16(g1.x), d1);
        d2 = fmaf(w1, lo16(g1.y), d2);
        d3 = fmaf(w1, hi16(g1.y), d3);
        c0 = fmaf(w2, lo16(g2.x), c0);
        c1 = fmaf(w2, hi16(g2.x), c1);
        c2 = fmaf(w2, lo16(g2.y), c2);
        c3 = fmaf(w2, hi16(g2.y), c3);
        d0 = fmaf(w3, lo16(g3.x), d0);
        d1 = fmaf(w3, hi16(g3.x), d1);
        d2 = fmaf(w3, lo16(g3.y), d2);
        d3 = fmaf(w3, hi16(g3.y), d3);
    }
    for (; j < end; j += 4) {
        uint2 e = csr[j];
        uint2 g = xp2[(size_t)e.x * 8 + u];
        float w = __uint_as_float(e.y);
        c0 = fmaf(w, lo16(g.x), c0);
        c1 = fmaf(w, hi16(g.x), c1);
        c2 = fmaf(w, lo16(g.y), c2);
        c3 = fmaf(w, hi16(g.y), c3);
    }
    c0 += d0; c1 += d1; c2 += d2; c3 += d3;
#pragma unroll
    for (int m = 8; m <= 16; m <<= 1) {          // reduce across 4 slots
        c0 += __shfl_xor(c0, m, 64);
        c1 += __shfl_xor(c1, m, 64);
        c2 += __shfl_xor(c2, m, 64);
        c3 += __shfl_xor(c3, m, 64);
    }
    if (s == 0) {
        float p0 = dn * (c0 + lo16(gs.x));
        float p1 = dn * (c1 + hi16(gs.x));
        float p2 = dn * (c2 + lo16(gs.y));
        float p3 = dn * (c3 + hi16(gs.y));
        pre[(size_t)n * 8 + u] = make_uint2(pack_bf16(p0, p1), pack_bf16(p2, p3));
    }
}

// ---------- dense MLP: pre -> GEMM1(+b1,relu) -> GEMM2 -> dn scale -> hw2p ----
__global__ __launch_bounds__(256) void k_mlp(
        const uint2* __restrict__ pre2, const float* __restrict__ dinv,
        const float* __restrict__ W1, const float* __restrict__ b1,
        const float* __restrict__ W2, unsigned* __restrict__ hw2p, int nwaves) {
    __shared__ float pre_lds[4 * FIN];
    __shared__ float hv_lds[4 * FHID];
    int lane = threadIdx.x & 63;
    int ws = threadIdx.x >> 6;
    int hh = lane >> 5;
    int f = lane & 31;
    int t = lane & 15;
    int o = lane;
    float W1col[FIN];
#pragma unroll
    for (int k = 0; k < FIN; ++k) W1col[k] = W1[k * FHID + o];
    float b1o = b1[o];
    float W2h[FIN];
#pragma unroll
    for (int k = 0; k < FIN; ++k) W2h[k] = W2[(hh * 32 + k) * FIN + f];

    int gw = (blockIdx.x * blockDim.x + threadIdx.x) >> 6;
    for (int n = gw; n < NN; n += nwaves) {
        float dn = dinv[n];
        if (lane < 8) {
            uint2 g = pre2[(size_t)n * 8 + lane];
            float4 pq = make_float4(lo16(g.x), hi16(g.x), lo16(g.y), hi16(g.y));
            *(float4*)&pre_lds[ws * FIN + 4 * lane] = pq;
        }
        LGKM0;
        float hacc = b1o;
#pragma unroll
        for (int i = 0; i < 8; ++i) {
            float4 qd = *(const float4*)&pre_lds[ws * FIN + 4 * i];
            hacc = fmaf(qd.x, W1col[4 * i + 0], hacc);
            hacc = fmaf(qd.y, W1col[4 * i + 1], hacc);
            hacc = fmaf(qd.z, W1col[4 * i + 2], hacc);
            hacc = fmaf(qd.w, W1col[4 * i + 3], hacc);
        }
        hacc = hacc > 0.0f ? hacc : 0.0f;
        hv_lds[ws * FHID + o] = hacc;
        LGKM0;
        float part = 0.0f;
#pragma unroll
        for (int i = 0; i < 8; ++i) {
            float4 qd = *(const float4*)&hv_lds[ws * FHID + hh * 32 + 4 * i];
            part = fmaf(qd.x, W2h[4 * i + 0], part);
            part = fmaf(qd.y, W2h[4 * i + 1], part);
            part = fmaf(qd.z, W2h[4 * i + 2], part);
            part = fmaf(qd.w, W2h[4 * i + 3], part);
        }
        part += __shfl_xor(part, 32, 64);
        float v = dn * part;
        float vlo = __shfl(v, 2 * t, 64);
        float vhi = __shfl(v, 2 * t + 1, 64);
        if (lane < 16) hw2p[(size_t)n * 16 + lane] = pack_bf16(vlo, vhi);
    }
}

// ---------- layer-2 pure aggregation, 2 nodes/wave, +bias+relu -> out ---------
__global__ __launch_bounds__(256) void k_agg2p(
        const unsigned* __restrict__ rowptrp, const uint2* __restrict__ csr,
        const uint2* __restrict__ hw2p2, const float* __restrict__ dinv,
        const float* __restrict__ b2, float* __restrict__ out) {
    int wid = (blockIdx.x * blockDim.x + threadIdx.x) >> 6;
    int lane = threadIdx.x & 63;
    int n = wid * 2 + (lane >> 5);
    if (n >= NN) return;
    int s = (lane & 31) >> 3;
    int u = lane & 7;
    unsigned rp = rowptrp[n];
    int beg = rp >> 10;
    int end = beg + (rp & 1023u);
    float dn = dinv[n];
    uint2 gs = hw2p2[(size_t)n * 8 + u];
    float c0 = 0.f, c1 = 0.f, c2 = 0.f, c3 = 0.f;
    float d0 = 0.f, d1 = 0.f, d2 = 0.f, d3 = 0.f;
    int j = beg + s;
    for (; j + 12 < end; j += 16) {
        uint2 e0 = csr[j];
        uint2 e1 = csr[j + 4];
        uint2 e2 = csr[j + 8];
        uint2 e3 = csr[j + 12];
        uint2 g0 = hw2p2[(size_t)e0.x * 8 + u];
        uint2 g1 = hw2p2[(size_t)e1.x * 8 + u];
        uint2 g2 = hw2p2[(size_t)e2.x * 8 + u];
        uint2 g3 = hw2p2[(size_t)e3.x * 8 + u];
        float w0 = __uint_as_float(e0.y);
        float w1 = __uint_as_float(e1.y);
        float w2 = __uint_as_float(e2.y);
        float w3 = __uint_as_float(e3.y);
        c0 = fmaf(w0, lo16(g0.x), c0);
        c1 = fmaf(w0, hi16(g0.x), c1);
        c2 = fmaf(w0, lo16(g0.y), c2);
        c3 = fmaf(w0, hi16(g0.y), c3);
        d0 = fmaf(w1, lo16(g1.x), d0);
        d1 = fmaf(w1, hi16(g1.x), d1);
        d2 = fmaf(w1, lo16(g1.y), d2);
        d3 = fmaf(w1, hi16(g1.y), d3);
        c0 = fmaf(w2, lo16(g2.x), c0);
        c1 = fmaf(w2, hi16(g2.x), c1);
        c2 = fmaf(w2, lo16(g2.y), c2);
        c3 = fmaf(w2, hi16(g2.y), c3);
        d0 = fmaf(w3, lo16(g3.x), d0);
        d1 = fmaf(w3, hi16(g3.x), d1);
        d2 = fmaf(w3, lo16(g3.y), d2);
        d3 = fmaf(w3, hi16(g3.y), d3);
    }
    for (; j < end; j += 4) {
        uint2 e = csr[j];
        uint2 g = hw2p2[(size_t)e.x * 8 + u];
        float w = __uint_as_float(e.y);
        c0 = fmaf(w, lo16(g.x), c0);
        c1 = fmaf(w, hi16(g.x), c1);
        c2 = fmaf(w, lo16(g.y), c2);
        c3 = fmaf(w, hi16(g.y), c3);
    }
    c0 += d0; c1 += d1; c2 += d2; c3 += d3;
#pragma unroll
    for (int m = 8; m <= 16; m <<= 1) {
        c0 += __shfl_xor(c0, m, 64);
        c1 += __shfl_xor(c1, m, 64);
        c2 += __shfl_xor(c2, m, 64);
        c3 += __shfl_xor(c3, m, 64);
    }
    if (s == 0) {
        float4 bq = ((const float4*)b2)[u];
        float4 v;
        v.x = dn * (c0 + lo16(gs.x)) + bq.x;
        v.y = dn * (c1 + hi16(gs.x)) + bq.y;
        v.z = dn * (c2 + lo16(gs.y)) + bq.z;
        v.w = dn * (c3 + hi16(gs.y)) + bq.w;
        v.x = v.x > 0.f ? v.x : 0.f;
        v.y = v.y > 0.f ? v.y : 0.f;
        v.z = v.z > 0.f ? v.z : 0.f;
        v.w = v.w > 0.f ? v.w : 0.f;
        ((float4*)out)[(size_t)n * 8 + u] = v;
    }
}

extern "C" void kernel_launch(void* const* d_in, const int* in_sizes, int n_in,
                              void* d_out, int out_size, void* d_ws, size_t ws_size,
                              hipStream_t stream) {
    const float* x  = (const float*)d_in[0];
    const int*   ei = (const int*)d_in[1];
    const float* ea = (const float*)d_in[2];
    const float* W1 = (const float*)d_in[3];
    const float* b1 = (const float*)d_in[4];
    const float* W2 = (const float*)d_in[5];
    const float* b2 = (const float*)d_in[6];
    float* out = (float*)d_out;

    const int* row = ei;        // edge_index[0]
    const int* col = ei + NE;   // edge_index[1]

    // workspace layout (~58 MB)
    char* w = (char*)d_ws;
    uint2* rec0     = (uint2*)w;                         // NB*CAP*8  (18.8 MB)
    uint2* csr      = rec0 + (size_t)NB * CAP;           // NB*CAP*8  (18.8 MB)
    unsigned* xp    = (unsigned*)(csr + (size_t)NB * CAP);   // NN*16 (bf16x2)
    unsigned* hw2p  = xp + (size_t)NN * 16;              // NN*16 (bf16x2)
    unsigned* pre   = hw2p + (size_t)NN * 16;            // NN*16 (bf16x2)
    float* dinv     = (float*)(pre + (size_t)NN * 16);   // NN
    unsigned* rowptrp = (unsigned*)(dinv + NN);          // NN
    int*   cnt_g    = (int*)(rowptrp + NN);              // NB

    auto cdiv = [](long long a, int b) { return (int)((a + b - 1) / b); };
    const int PAIR_BLOCKS = cdiv((long long)cdiv(NN, 2) * 64, 256);  // 12500

    // build: zero bucket cursors, distribute (+ea passthrough), bucket sort
    hipMemsetAsync(cnt_g, 0, sizeof(int) * NB, stream);
    k_dwrite<<<NDB, NDT, 0, stream>>>(row, col, ea, cnt_g, rec0,
                                      out + (size_t)NN * FIN);
    k_bsort<<<NB, 512, 0, stream>>>(cnt_g, rec0, x, csr, rowptrp, dinv, xp);

    // layer 1: pure agg -> pre (bf16), dense MLP -> hw2p (bf16)
    k_agg1p<<<PAIR_BLOCKS, 256, 0, stream>>>(rowptrp, csr, (const uint2*)xp,
                                             dinv, (uint2*)pre);
    const int MLP_BLOCKS = 2048;
    k_mlp<<<MLP_BLOCKS, 256, 0, stream>>>((const uint2*)pre, dinv, W1, b1, W2,
                                          hw2p, MLP_BLOCKS * 4);

    // layer 2: pure agg (+bias, relu) -> out
    k_agg2p<<<PAIR_BLOCKS, 256, 0, stream>>>(rowptrp, csr, (const uint2*)hw2p,
                                             dinv, b2, out);
}

// Round 16
// 143.012 us; speedup vs baseline: 1.0900x; 1.0415x over previous
//
#include <hip/hip_runtime.h>

#define NN 100000
#define NE 1600000
#define FIN 32
#define FHID 64

#define CLB 8                                   // log2(nodes per bucket)
#define BN (1 << CLB)                           // 256 nodes / bucket
#define NB ((NN + BN - 1) / BN)                 // 391 buckets
#define CAP 6000                                // record capacity per bucket (+30 sigma)
#define NDB 256                                 // distributor blocks (1/CU)
#define NDT 1024                                // distributor threads (16 waves)
#define CHUNK ((NE + NDB - 1) / NDB)            // 6250 edges / distributor block
#define RCAP 12                                 // 512*12 = 6144 >= CAP

#define LGKM0 asm volatile("s_waitcnt lgkmcnt(0)" ::: "memory")

__device__ __forceinline__ float lo16(unsigned g) {
    return __uint_as_float(g << 16);
}
__device__ __forceinline__ float hi16(unsigned g) {
    return __uint_as_float(g & 0xFFFF0000u);
}
__device__ __forceinline__ unsigned pack_bf16(float a, float b) {
    unsigned ua = __float_as_uint(a);
    unsigned ub = __float_as_uint(b);
    ua += 0x7FFFu + ((ua >> 16) & 1u);          // RNE
    ub += 0x7FFFu + ((ub >> 16) & 1u);
    return (ua >> 16) | (ub & 0xFFFF0000u);
}

// ---------- distribute: LDS hist -> atomic slice reservation -> write ---------
// record = ((col_local << 17) | src, ew_bits); fused edge_attr passthrough.
__global__ __launch_bounds__(NDT) void k_dwrite(
        const int* __restrict__ row, const int* __restrict__ col,
        const float* __restrict__ ea, int* __restrict__ cnt_g,
        uint2* __restrict__ rec0, float* __restrict__ out_ea) {
    __shared__ int hc[NB];
    __shared__ int bl[NB];
    int tid = threadIdx.x;
    for (int i = tid; i < NB; i += NDT) hc[i] = 0;
    __syncthreads();
    int beg = blockIdx.x * CHUNK, end = min(beg + CHUNK, NE);
    for (int e = beg + tid; e < end; e += NDT)
        atomicAdd(&hc[col[e] >> CLB], 1);
    __syncthreads();
    for (int i = tid; i < NB; i += NDT) {
        int c = hc[i];
        bl[i] = i * CAP + (c ? atomicAdd(&cnt_g[i], c) : 0);
        hc[i] = 0;                              // reuse as local rank
    }
    __syncthreads();
    for (int e = beg + tid; e < end; e += NDT) {
        int c = col[e];
        int bk = c >> CLB;
        int r = atomicAdd(&hc[bk], 1);
        float w = ea[e];
        rec0[bl[bk] + r] = make_uint2(((unsigned)(c & (BN - 1)) << 17) |
                                          (unsigned)row[e],
                                      __float_as_uint(w));
        out_ea[e] = w;                          // fused passthrough output
    }
}

// ---------- per-bucket sort -> packed rowptr + dinv + xp packing --------------
// rowptrp[n] = (csr_pos << 10) | in_degree   (pos < 2^22, deg < 1024)
__global__ __launch_bounds__(512) void k_bsort(
        const int* __restrict__ cnt_g, const uint2* __restrict__ rec0,
        const float* __restrict__ x, uint2* __restrict__ csr,
        unsigned* __restrict__ rowptrp, float* __restrict__ dinv,
        unsigned* __restrict__ xp) {
    __shared__ int cnt[BN];
    __shared__ int bas[BN];
    __shared__ int cur[BN];
    __shared__ float dg[BN];
    __shared__ float dl[BN];
    int tid = threadIdx.x;
    int b = blockIdx.x;
    int base = b * CAP;
    int m = cnt_g[b];
    if (tid < BN) { cnt[tid] = 0; dg[tid] = 0.0f; }
    __syncthreads();
    uint2 rc[RCAP];
#pragma unroll
    for (int i = 0; i < RCAP; ++i) {
        int j = tid + i * 512;
        if (j < m) {
            uint2 p = rec0[base + j];
            rc[i] = p;
            atomicAdd(&cnt[p.x >> 17], 1);
            atomicAdd(&dg[p.x >> 17], __uint_as_float(p.y));
        } else {
            rc[i] = make_uint2(0u, 0u);
        }
    }
    __syncthreads();
    int v0 = (tid < BN) ? cnt[tid] : 0;
    __syncthreads();
    for (int o = 1; o < BN; o <<= 1) {               // Hillis-Steele inclusive
        int t = (tid < BN && tid >= o) ? cnt[tid - o] : 0;
        __syncthreads();
        if (tid < BN) cnt[tid] += t;
        __syncthreads();
    }
    if (tid < BN) {
        int excl = cnt[tid] - v0;
        bas[tid] = excl;
        cur[tid] = 0;
        float dn = rsqrtf(1.0f + dg[tid]);           // self-loop weight 1
        dl[tid] = dn;
        int node = b * BN + tid;
        if (node < NN) {
            rowptrp[node] = ((unsigned)(base + excl) << 10) | (unsigned)v0;
            dinv[node] = dn;
        }
    }
    __syncthreads();
#pragma unroll
    for (int i = 0; i < RCAP; ++i) {
        int j = tid + i * 512;
        if (j < m) {
            uint2 p = rc[i];
            int cl = p.x >> 17;
            int r = atomicAdd(&cur[cl], 1);
            csr[base + bas[cl] + r] = make_uint2(p.x & 0x1FFFFu, p.y);
        }
    }
    // fused scalex: xp = bf16x2(dinv * x) for this bucket's nodes
    for (int idx = tid; idx < BN * (FIN / 2); idx += 512) {
        int nl = idx >> 4;
        int node = b * BN + nl;
        if (node >= NN) break;
        float dn = dl[nl];
        float2 v = ((const float2*)x)[(size_t)node * 16 + (idx & 15)];
        xp[(size_t)node * 16 + (idx & 15)] = pack_bf16(v.x * dn, v.y * dn);
    }
}

// ---------- pure aggregation, 2 nodes/wave, 4-deep gather unroll --------------
__global__ __launch_bounds__(256) void k_agg1p(
        const unsigned* __restrict__ rowptrp, const uint2* __restrict__ csr,
        const uint2* __restrict__ xp2, const float* __restrict__ dinv,
        uint2* __restrict__ pre) {
    int wid = (blockIdx.x * blockDim.x + threadIdx.x) >> 6;
    int lane = threadIdx.x & 63;
    int n = wid * 2 + (lane >> 5);
    if (n >= NN) return;
    int s = (lane & 31) >> 3;
    int u = lane & 7;
    unsigned rp = rowptrp[n];
    int beg = rp >> 10;
    int end = beg + (rp & 1023u);
    float dn = dinv[n];
    uint2 gs = xp2[(size_t)n * 8 + u];
    float c0 = 0.f, c1 = 0.f, c2 = 0.f, c3 = 0.f;
    float d0 = 0.f, d1 = 0.f, d2 = 0.f, d3 = 0.f;
    int j = beg + s;
    for (; j + 12 < end; j += 16) {
        uint2 e0 = csr[j];
        uint2 e1 = csr[j + 4];
        uint2 e2 = csr[j + 8];
        uint2 e3 = csr[j + 12];
        uint2 g0 = xp2[(size_t)e0.x * 8 + u];
        uint2 g1 = xp2[(size_t)e1.x * 8 + u];
        uint2 g2 = xp2[(size_t)e2.x * 8 + u];
        uint2 g3 = xp2[(size_t)e3.x * 8 + u];
        float w0 = __uint_as_float(e0.y);
        float w1 = __uint_as_float(e1.y);
        float w2 = __uint_as_float(e2.y);
        float w3 = __uint_as_float(e3.y);
        c0 = fmaf(w0, lo16(g0.x), c0);
        c1 = fmaf(w0, hi16(g0.x), c1);
        c2 = fmaf(w0, lo16(g0.y), c2);
        c3 = fmaf(w0, hi16(g0.y), c3);
        d0 = fmaf(w1, lo16(g1.x), d0);
        d1 = fmaf(w1, hi16(g1.x), d1);
        d2 = fmaf(w1, lo16(g1.y), d2);
        d3 = fmaf(w1, hi16(g1.y), d3);
        c0 = fmaf(w2, lo16(g2.x), c0);
        c1 = fmaf(w2, hi16(g2.x), c1);
        c2 = fmaf(w2, lo16(g2.y), c2);
        c3 = fmaf(w2, hi16(g2.y), c3);
        d0 = fmaf(w3, lo16(g3.x), d0);
        d1 = fmaf(w3, hi16(g3.x), d1);
        d2 = fmaf(w3, lo16(g3.y), d2);
        d3 = fmaf(w3, hi16(g3.y), d3);
    }
    for (; j < end; j += 4) {
        uint2 e = csr[j];
        uint2 g = xp2[(size_t)e.x * 8 + u];
        float w = __uint_as_float(e.y);
        c0 = fmaf(w, lo16(g.x), c0);
        c1 = fmaf(w, hi16(g.x), c1);
        c2 = fmaf(w, lo16(g.y), c2);
        c3 = fmaf(w, hi16(g.y), c3);
    }
    c0 += d0; c1 += d1; c2 += d2; c3 += d3;
#pragma unroll
    for (int m = 8; m <= 16; m <<= 1) {          // reduce across 4 slots
        c0 += __shfl_xor(c0, m, 64);
        c1 += __shfl_xor(c1, m, 64);
        c2 += __shfl_xor(c2, m, 64);
        c3 += __shfl_xor(c3, m, 64);
    }
    if (s == 0) {
        float p0 = dn * (c0 + lo16(gs.x));
        float p1 = dn * (c1 + hi16(gs.x));
        float p2 = dn * (c2 + lo16(gs.y));
        float p3 = dn * (c3 + hi16(gs.y));
        pre[(size_t)n * 8 + u] = make_uint2(pack_bf16(p0, p1), pack_bf16(p2, p3));
    }
}

// ---------- dense MLP: pre -> GEMM1(+b1,relu) -> GEMM2 -> dn scale -> hw2p ----
__global__ __launch_bounds__(256) void k_mlp(
        const uint2* __restrict__ pre2, const float* __restrict__ dinv,
        const float* __restrict__ W1, const float* __restrict__ b1,
        const float* __restrict__ W2, unsigned* __restrict__ hw2p, int nwaves) {
    __shared__ float pre_lds[4 * FIN];
    __shared__ float hv_lds[4 * FHID];
    int lane = threadIdx.x & 63;
    int ws = threadIdx.x >> 6;
    int hh = lane >> 5;
    int f = lane & 31;
    int t = lane & 15;
    int o = lane;
    float W1col[FIN];
#pragma unroll
    for (int k = 0; k < FIN; ++k) W1col[k] = W1[k * FHID + o];
    float b1o = b1[o];
    float W2h[FIN];
#pragma unroll
    for (int k = 0; k < FIN; ++k) W2h[k] = W2[(hh * 32 + k) * FIN + f];

    int gw = (blockIdx.x * blockDim.x + threadIdx.x) >> 6;
    for (int n = gw; n < NN; n += nwaves) {
        float dn = dinv[n];
        if (lane < 8) {
            uint2 g = pre2[(size_t)n * 8 + lane];
            float4 pq = make_float4(lo16(g.x), hi16(g.x), lo16(g.y), hi16(g.y));
            *(float4*)&pre_lds[ws * FIN + 4 * lane] = pq;
        }
        LGKM0;
        float hacc = b1o;
#pragma unroll
        for (int i = 0; i < 8; ++i) {
            float4 qd = *(const float4*)&pre_lds[ws * FIN + 4 * i];
            hacc = fmaf(qd.x, W1col[4 * i + 0], hacc);
            hacc = fmaf(qd.y, W1col[4 * i + 1], hacc);
            hacc = fmaf(qd.z, W1col[4 * i + 2], hacc);
            hacc = fmaf(qd.w, W1col[4 * i + 3], hacc);
        }
        hacc = hacc > 0.0f ? hacc : 0.0f;
        hv_lds[ws * FHID + o] = hacc;
        LGKM0;
        float part = 0.0f;
#pragma unroll
        for (int i = 0; i < 8; ++i) {
            float4 qd = *(const float4*)&hv_lds[ws * FHID + hh * 32 + 4 * i];
            part = fmaf(qd.x, W2h[4 * i + 0], part);
            part = fmaf(qd.y, W2h[4 * i + 1], part);
            part = fmaf(qd.z, W2h[4 * i + 2], part);
            part = fmaf(qd.w, W2h[4 * i + 3], part);
        }
        part += __shfl_xor(part, 32, 64);
        float v = dn * part;
        float vlo = __shfl(v, 2 * t, 64);
        float vhi = __shfl(v, 2 * t + 1, 64);
        if (lane < 16) hw2p[(size_t)n * 16 + lane] = pack_bf16(vlo, vhi);
    }
}

// ---------- layer-2 pure aggregation, 2 nodes/wave, +bias+relu -> out ---------
__global__ __launch_bounds__(256) void k_agg2p(
        const unsigned* __restrict__ rowptrp, const uint2* __restrict__ csr,
        const uint2* __restrict__ hw2p2, const float* __restrict__ dinv,
        const float* __restrict__ b2, float* __restrict__ out) {
    int wid = (blockIdx.x * blockDim.x + threadIdx.x) >> 6;
    int lane = threadIdx.x & 63;
    int n = wid * 2 + (lane >> 5);
    if (n >= NN) return;
    int s = (lane & 31) >> 3;
    int u = lane & 7;
    unsigned rp = rowptrp[n];
    int beg = rp >> 10;
    int end = beg + (rp & 1023u);
    float dn = dinv[n];
    uint2 gs = hw2p2[(size_t)n * 8 + u];
    float c0 = 0.f, c1 = 0.f, c2 = 0.f, c3 = 0.f;
    float d0 = 0.f, d1 = 0.f, d2 = 0.f, d3 = 0.f;
    int j = beg + s;
    for (; j + 12 < end; j += 16) {
        uint2 e0 = csr[j];
        uint2 e1 = csr[j + 4];
        uint2 e2 = csr[j + 8];
        uint2 e3 = csr[j + 12];
        uint2 g0 = hw2p2[(size_t)e0.x * 8 + u];
        uint2 g1 = hw2p2[(size_t)e1.x * 8 + u];
        uint2 g2 = hw2p2[(size_t)e2.x * 8 + u];
        uint2 g3 = hw2p2[(size_t)e3.x * 8 + u];
        float w0 = __uint_as_float(e0.y);
        float w1 = __uint_as_float(e1.y);
        float w2 = __uint_as_float(e2.y);
        float w3 = __uint_as_float(e3.y);
        c0 = fmaf(w0, lo16(g0.x), c0);
        c1 = fmaf(w0, hi16(g0.x), c1);
        c2 = fmaf(w0, lo16(g0.y), c2);
        c3 = fmaf(w0, hi16(g0.y), c3);
        d0 = fmaf(w1, lo16(g1.x), d0);
        d1 = fmaf(w1, hi16(g1.x), d1);
        d2 = fmaf(w1, lo16(g1.y), d2);
        d3 = fmaf(w1, hi16(g1.y), d3);
        c0 = fmaf(w2, lo16(g2.x), c0);
        c1 = fmaf(w2, hi16(g2.x), c1);
        c2 = fmaf(w2, lo16(g2.y), c2);
        c3 = fmaf(w2, hi16(g2.y), c3);
        d0 = fmaf(w3, lo16(g3.x), d0);
        d1 = fmaf(w3, hi16(g3.x), d1);
        d2 = fmaf(w3, lo16(g3.y), d2);
        d3 = fmaf(w3, hi16(g3.y), d3);
    }
    for (; j < end; j += 4) {
        uint2 e = csr[j];
        uint2 g = hw2p2[(size_t)e.x * 8 + u];
        float w = __uint_as_float(e.y);
        c0 = fmaf(w, lo16(g.x), c0);
        c1 = fmaf(w, hi16(g.x), c1);
        c2 = fmaf(w, lo16(g.y), c2);
        c3 = fmaf(w, hi16(g.y), c3);
    }
    c0 += d0; c1 += d1; c2 += d2; c3 += d3;
#pragma unroll
    for (int m = 8; m <= 16; m <<= 1) {
        c0 += __shfl_xor(c0, m, 64);
        c1 += __shfl_xor(c1, m, 64);
        c2 += __shfl_xor(c2, m, 64);
        c3 += __shfl_xor(c3, m, 64);
    }
    if (s == 0) {
        float4 bq = ((const float4*)b2)[u];
        float4 v;
        v.x = dn * (c0 + lo16(gs.x)) + bq.x;
        v.y = dn * (c1 + hi16(gs.x)) + bq.y;
        v.z = dn * (c2 + lo16(gs.y)) + bq.z;
        v.w = dn * (c3 + hi16(gs.y)) + bq.w;
        v.x = v.x > 0.f ? v.x : 0.f;
        v.y = v.y > 0.f ? v.y : 0.f;
        v.z = v.z > 0.f ? v.z : 0.f;
        v.w = v.w > 0.f ? v.w : 0.f;
        ((float4*)out)[(size_t)n * 8 + u] = v;
    }
}

extern "C" void kernel_launch(void* const* d_in, const int* in_sizes, int n_in,
                              void* d_out, int out_size, void* d_ws, size_t ws_size,
                              hipStream_t stream) {
    const float* x  = (const float*)d_in[0];
    const int*   ei = (const int*)d_in[1];
    const float* ea = (const float*)d_in[2];
    const float* W1 = (const float*)d_in[3];
    const float* b1 = (const float*)d_in[4];
    const float* W2 = (const float*)d_in[5];
    const float* b2 = (const float*)d_in[6];
    float* out = (float*)d_out;

    const int* row = ei;        // edge_index[0]
    const int* col = ei + NE;   // edge_index[1]

    // workspace layout (~58 MB)
    char* w = (char*)d_ws;
    uint2* rec0     = (uint2*)w;                         // NB*CAP*8  (18.8 MB)
    uint2* csr      = rec0 + (size_t)NB * CAP;           // NB*CAP*8  (18.8 MB)
    unsigned* xp    = (unsigned*)(csr + (size_t)NB * CAP);   // NN*16 (bf16x2)
    unsigned* hw2p  = xp + (size_t)NN * 16;              // NN*16 (bf16x2)
    unsigned* pre   = hw2p + (size_t)NN * 16;            // NN*16 (bf16x2)
    float* dinv     = (float*)(pre + (size_t)NN * 16);   // NN
    unsigned* rowptrp = (unsigned*)(dinv + NN);          // NN
    int*   cnt_g    = (int*)(rowptrp + NN);              // NB

    auto cdiv = [](long long a, int b) { return (int)((a + b - 1) / b); };
    const int PAIR_BLOCKS = cdiv((long long)cdiv(NN, 2) * 64, 256);  // 12500

    // build: zero bucket cursors, distribute (+ea passthrough), bucket sort
    hipMemsetAsync(cnt_g, 0, sizeof(int) * NB, stream);
    k_dwrite<<<NDB, NDT, 0, stream>>>(row, col, ea, cnt_g, rec0,
                                      out + (size_t)NN * FIN);
    k_bsort<<<NB, 512, 0, stream>>>(cnt_g, rec0, x, csr, rowptrp, dinv, xp);

    // layer 1: pure agg -> pre (bf16), dense MLP -> hw2p (bf16)
    k_agg1p<<<PAIR_BLOCKS, 256, 0, stream>>>(rowptrp, csr, (const uint2*)xp,
                                             dinv, (uint2*)pre);
    const int MLP_BLOCKS = 2048;
    k_mlp<<<MLP_BLOCKS, 256, 0, stream>>>((const uint2*)pre, dinv, W1, b1, W2,
                                          hw2p, MLP_BLOCKS * 4);

    // layer 2: pure agg (+bias, relu) -> out
    k_agg2p<<<PAIR_BLOCKS, 256, 0, stream>>>(rowptrp, csr, (const uint2*)hw2p,
                                             dinv, b2, out);
}